// Round 5
// baseline (174.770 us; speedup 1.0000x reference)
//
#include <hip/hip_runtime.h>

// Problem constants (hardcoded; spatial_shapes = [[4,8]]*4)
//  bs=64, nq=64, E=256, Hn=8, dh=32, L=4, P=16, BEV=2, Pb=32
//  qb=128 collapses to 64. OFF col (h,f,c)=h*256+2f+c; rp level = f&3;
//  image level = f>>5 = wave; attn key = f; output pairs (2q,2q+1) -> pj/pj+32.
//
// mega6b (this round): CODE-SIZE experiment. R0-R4 ruled out barriers, LDS
// staging, occupancy, and launch overhead; per-block busy-cycle model is 15x
// below measured -> shared stalled resource. Suspect: L1I (32KB) thrash —
// all variants are ~50-60KB of straight-line code streamed once per wave.
// Fix: roll the big loops (kq GEMM, VTl stage, Am zero, Phase C) with
// #pragma unroll 1 -> static footprint ~22KB + loop reuse. Algorithm,
// numerics, launch identical to mega6 (absmax must stay 0.03125).

typedef short  s16x8 __attribute__((ext_vector_type(8)));
typedef float  f32x4 __attribute__((ext_vector_type(4)));

__device__ __forceinline__ unsigned short f2bf(float f) {
    union { float f; unsigned u; } v; v.f = f;
    unsigned r = v.u + 0x7FFFu + ((v.u >> 16) & 1u);   // RNE
    return (unsigned short)(r >> 16);
}
__device__ __forceinline__ float bf2f(unsigned short u) {
    return __uint_as_float(((unsigned)u) << 16);
}
// 8 consecutive f32 -> bf16x8 (row-major run)
__device__ __forceinline__ s16x8 ld8bf(const float* __restrict__ p) {
    const float4 v0 = *(const float4*)p;
    const float4 v1 = *(const float4*)(p + 4);
    s16x8 o;
    o[0] = (short)f2bf(v0.x); o[1] = (short)f2bf(v0.y);
    o[2] = (short)f2bf(v0.z); o[3] = (short)f2bf(v0.w);
    o[4] = (short)f2bf(v1.x); o[5] = (short)f2bf(v1.y);
    o[6] = (short)f2bf(v1.z); o[7] = (short)f2bf(v1.w);
    return o;
}
// W column gather: 8 consecutive k (rows of W), fixed n. Coalesced across
// lanes (lane index varies n by +1).
__device__ __forceinline__ s16x8 ldcol8bf(const float* __restrict__ W,
                                          int k, int n) {
    s16x8 o;
    #pragma unroll
    for (int j = 0; j < 8; ++j)
        o[j] = (short)f2bf(W[(size_t)(k + j) * 2048 + n]);
    return o;
}

// ---------------------------------------------------------------------------
// mega6b: one block per (b,h). LDS 79360 B -> 2 blocks/CU. 3 barriers.
// ---------------------------------------------------------------------------
__global__ __launch_bounds__(256, 2) void mega6b(
    const float* __restrict__ query, const float* __restrict__ key_hist,
    const float* __restrict__ value_hist, const float* __restrict__ refp,
    const float* __restrict__ W, const float* __restrict__ bias,
    float* __restrict__ out)
{
    const int b = blockIdx.x, h = blockIdx.y;
    const int t = threadIdx.x, lane = t & 63, wave = t >> 6;
    const int quad = lane >> 4, col = lane & 15;
    const int wq = wave * 16;

    __shared__ __align__(16) short VTl[32 * 136];   // V^T [d][p], 8704 B
    __shared__ __align__(16) short attLb[64 * 136]; // att probs bf16, 17408 B
    __shared__ __align__(16) float rpsL[512];       // refp rows, 2048 B
    __shared__ __align__(16) float Am[64 * 132];    // scatter acc f32, 33792 B
    __shared__ __align__(16) short Amb[64 * 136];   // scatter acc bf16, 17408 B

    // ============ Phase A: everything before the first barrier ============
    // A1: stage VTl (values = [query rows | value_hist rows], h-slice, ^T)
    //     ROLLED: locals only, no static-index requirement.
    {
        const int p = t >> 1, hf = (t & 1) * 16;
        const float* src = ((p < 64) ? query : value_hist) +
                           (size_t)(b * 64 + (p & 63)) * 256 + h * 32 + hf;
        #pragma unroll 1
        for (int u = 0; u < 4; ++u) {
            const float4 v = *(const float4*)(src + 4 * u);
            VTl[(hf + 4 * u + 0) * 136 + p] = (short)f2bf(v.x);
            VTl[(hf + 4 * u + 1) * 136 + p] = (short)f2bf(v.y);
            VTl[(hf + 4 * u + 2) * 136 + p] = (short)f2bf(v.z);
            VTl[(hf + 4 * u + 3) * 136 + p] = (short)f2bf(v.w);
        }
    }
    // A2: refp rows + zero Am (ROLLED)
    rpsL[t]       = refp[(size_t)b * 512 + t];
    rpsL[t + 256] = refp[(size_t)b * 512 + t + 256];
    #pragma unroll 1
    for (int u = 0; u < 33; ++u) Am[t + 256 * u] = 0.f;

    // A3: offsets GEMM, N-split: wave owns n' in [64*wave, +64).
    //     acc[mi][nj]; q = 16mi+4quad+reg, n' = 64*wave + 16nj + col.
    //     kq loop ROLLED (acc indices independent of kq -> stays in regs);
    //     inner frag loops unrolled (static indexing).
    f32x4 acc[4][4] = {};
    #pragma unroll 1
    for (int kq = 0; kq < 4; ++kq) {
        s16x8 afp[4][2], bfp[4][2];
        #pragma unroll
        for (int mi = 0; mi < 4; ++mi)
            #pragma unroll
            for (int ks = 0; ks < 2; ++ks)
                afp[mi][ks] = ld8bf(query +
                    ((size_t)b * 64 + 16 * mi + col) * 256
                    + kq * 64 + ks * 32 + quad * 8);
        #pragma unroll
        for (int nj = 0; nj < 4; ++nj)
            #pragma unroll
            for (int ks = 0; ks < 2; ++ks)
                bfp[nj][ks] = ldcol8bf(W,
                    kq * 64 + ks * 32 + quad * 8,
                    h * 256 + wave * 64 + 16 * nj + col);
        #pragma unroll
        for (int ks = 0; ks < 2; ++ks)
            #pragma unroll
            for (int mi = 0; mi < 4; ++mi)
                #pragma unroll
                for (int nj = 0; nj < 4; ++nj)
                    acc[mi][nj] = __builtin_amdgcn_mfma_f32_16x16x32_bf16(
                        afp[mi][ks], bfp[nj][ks], acc[mi][nj], 0, 0, 0);
    }

    // A4: logits + softmax -> attLb (wave's q-strip rows).
    //     lacc[8]/e[8] need static indexing -> stays unrolled.
    {
        const s16x8 aq = ld8bf(query +
            ((size_t)b * 64 + wq + col) * 256 + h * 32 + quad * 8);
        f32x4 lacc[8];
        #pragma unroll
        for (int t8 = 0; t8 < 8; ++t8) {
            const float* src = (t8 < 4)
                ? (query    + ((size_t)b * 64 + 16 * t8 + col) * 256)
                : (key_hist + ((size_t)b * 64 + 16 * (t8 - 4) + col) * 256);
            const s16x8 bk = ld8bf(src + h * 32 + quad * 8);
            const f32x4 z = {0.f, 0.f, 0.f, 0.f};
            lacc[t8] = __builtin_amdgcn_mfma_f32_16x16x32_bf16(aq, bk, z, 0, 0, 0);
        }
        #pragma unroll
        for (int r = 0; r < 4; ++r) {
            float m = lacc[0][r];
            #pragma unroll
            for (int t8 = 1; t8 < 8; ++t8) m = fmaxf(m, lacc[t8][r]);
            #pragma unroll
            for (int s = 1; s < 16; s <<= 1) m = fmaxf(m, __shfl_xor(m, s, 64));
            float e[8], ssum = 0.f;
            #pragma unroll
            for (int t8 = 0; t8 < 8; ++t8) {
                e[t8] = __expf(lacc[t8][r] - m); ssum += e[t8];
            }
            #pragma unroll
            for (int s = 1; s < 16; s <<= 1) ssum += __shfl_xor(ssum, s, 64);
            const float inv = 1.0f / ssum;
            const int q = wq + 4 * quad + r;
            #pragma unroll
            for (int t8 = 0; t8 < 8; ++t8)
                attLb[q * 136 + 16 * t8 + col] = (short)f2bf(e[t8] * inv);
        }
    }

    // A5: bias prefetch for this wave's n' columns (static for scatter)
    float bjv[4];
    #pragma unroll
    for (int nj = 0; nj < 4; ++nj)
        bjv[nj] = bias[h * 256 + wave * 64 + 16 * nj + col];

    __syncthreads();   // B1: VTl, rpsL, Am-zero, attLb all visible

    // ============ Phase B: bilinear scatter (wave w -> level w cols) =======
    // Unrolled: acc[mi][nj]/bjv[nj] need static indices (rule #20).
    {
        const int i   = col >> 1;          // f-sub 0..7 ; rp level = i&3
        const int par = col & 1;           // 0: x-coords, 1: y-coords
        const int base = 32 * wave;        // image level = f>>5 = wave
        #pragma unroll
        for (int nj = 0; nj < 4; ++nj) {
            const int f = 32 * wave + 8 * nj + i;
            #pragma unroll
            for (int mi = 0; mi < 4; ++mi) {
                float v[4], p[4];
                #pragma unroll
                for (int r = 0; r < 4; ++r) v[r] = acc[mi][nj][r] + bjv[nj];
                #pragma unroll
                for (int r = 0; r < 4; ++r) p[r] = __shfl_xor(v[r], 1, 64);
                #pragma unroll
                for (int rs = 0; rs < 2; ++rs) {
                    const int r = par * 2 + rs;
                    const float ox = par ? p[r] : v[r];
                    const float oy = par ? v[r] : p[r];
                    const int q = 16 * mi + 4 * quad + r;
                    const float2 rp = *(const float2*)&rpsL[q * 8 + (i & 3) * 2];
                    const float a = bf2f((unsigned short)attLb[q * 136 + f]);
                    const float gx = 8.f * (rp.x + ox * 0.125f) - 0.5f;
                    const float gy = 4.f * (rp.y + oy * 0.25f) - 0.5f;
                    const float x0f = floorf(gx), y0f = floorf(gy);
                    const float wx = gx - x0f, wy = gy - y0f;
                    const int x0 = (int)x0f, y0 = (int)y0f;
                    float* rowW = &Am[q * 132 + base];
                    const bool xv0 = (x0 >= 0) && (x0 < 8);
                    const bool xv1 = (x0 >= -1) && (x0 < 7);
                    const bool yv0 = (y0 >= 0) && (y0 < 4);
                    const bool yv1 = (y0 >= -1) && (y0 < 3);
                    if (xv0 && yv0) unsafeAtomicAdd(&rowW[y0 * 8 + x0],           a * (1.f - wx) * (1.f - wy));
                    if (xv1 && yv0) unsafeAtomicAdd(&rowW[y0 * 8 + x0 + 1],       a * wx * (1.f - wy));
                    if (xv0 && yv1) unsafeAtomicAdd(&rowW[(y0 + 1) * 8 + x0],     a * (1.f - wx) * wy);
                    if (xv1 && yv1) unsafeAtomicAdd(&rowW[(y0 + 1) * 8 + x0 + 1], a * wx * wy);
                }
            }
        }
    }
    __syncthreads();   // B2: scatter complete

    // ============ Phase C: Am(f32) -> Amb(bf16) (ROLLED) ===================
    {
        const int cq = t >> 2, cc = (t & 3) * 32;
        #pragma unroll 1
        for (int u = 0; u < 4; ++u) {
            const f32x4 v0 = *(const f32x4*)&Am[cq * 132 + cc + 8 * u];
            const f32x4 v1 = *(const f32x4*)&Am[cq * 132 + cc + 8 * u + 4];
            s16x8 o;
            o[0] = (short)f2bf(v0[0]); o[1] = (short)f2bf(v0[1]);
            o[2] = (short)f2bf(v0[2]); o[3] = (short)f2bf(v0[3]);
            o[4] = (short)f2bf(v1[0]); o[5] = (short)f2bf(v1[1]);
            o[6] = (short)f2bf(v1[2]); o[7] = (short)f2bf(v1[3]);
            *(s16x8*)&Amb[cq * 136 + cc + u * 8] = o;
        }
    }
    __syncthreads();   // B3: Amb ready

    // ============ Phase D: AV MFMA + pair-mean + residual ==================
    {
        f32x4 oacc[2] = {};
        #pragma unroll
        for (int ks = 0; ks < 4; ++ks) {
            const s16x8 af = *(const s16x8*)&Amb[(wq + col) * 136 + ks * 32 + quad * 8];
            #pragma unroll
            for (int n2 = 0; n2 < 2; ++n2) {
                const s16x8 bv = *(const s16x8*)&VTl[(n2 * 16 + col) * 136
                                                     + ks * 32 + quad * 8];
                oacc[n2] = __builtin_amdgcn_mfma_f32_16x16x32_bf16(af, bv, oacc[n2], 0, 0, 0);
            }
        }
        #pragma unroll
        for (int n2 = 0; n2 < 2; ++n2) {
            const int d = h * 32 + n2 * 16 + col;
            #pragma unroll
            for (int pr = 0; pr < 2; ++pr) {
                const float avg = 0.5f * (oacc[n2][2 * pr] + oacc[n2][2 * pr + 1]);
                const int pj = wave * 8 + quad * 2 + pr;
                const size_t re = ((size_t)b * 64 + pj) * 256 + d;
                const size_t ro = ((size_t)b * 64 + pj + 32) * 256 + d;
                out[re] = query[re] + avg;
                out[ro] = query[ro] + avg;
            }
        }
    }
}

extern "C" void kernel_launch(void* const* d_in, const int* in_sizes, int n_in,
                              void* d_out, int out_size, void* d_ws, size_t ws_size,
                              hipStream_t stream) {
    (void)in_sizes; (void)n_in; (void)out_size; (void)d_ws; (void)ws_size;
    const float* query      = (const float*)d_in[0];
    const float* key_hist   = (const float*)d_in[1];
    const float* value_hist = (const float*)d_in[2];
    const float* refp       = (const float*)d_in[3];
    const float* W_off      = (const float*)d_in[5];
    const float* b_off      = (const float*)d_in[6];
    float* out = (float*)d_out;

    // grid (b, h): linear id = b + 64h -> XCD = b%8
    mega6b<<<dim3(64, 8), 256, 0, stream>>>(query, key_hist, value_hist, refp,
                                            W_off, b_off, out);
}

// Round 7
// 164.961 us; speedup vs baseline: 1.0595x; 1.0595x over previous
//
#include <hip/hip_runtime.h>

// Problem constants (hardcoded; spatial_shapes = [[4,8]]*4)
//  bs=64, nq=64, E=256, Hn=8, dh=32, L=4, P=16, BEV=2, Pb=32
//  qb=128 collapses to 64 (queries duplicated). OFF col (h,f,c)=h*256+2f+c;
//  rp level = f&3; image level = f>>5 = wave; attn key = f;
//  output pairs (2q,2q+1) -> rows pj / pj+32.
//
// ws: [0,1M) Wtb bf16 [2048][256] | [1M,3M) Qb bf16 [4096][256]
//     [3M,5M) Khb bf16 [4096][256]
//
// mega7b (this round): R0's mega2 VERBATIM + Phase-P MLP burst, with the
// R6 race FIXED: the burst now dumps into a DEDICATED 4KB LDS buffer that
// nothing ever reads (R6 aliased it onto AmU/Bsl; the compiler is free to
// hoist Phase-1 loads above the burst, so burst lines could land after Bsl
// staging -> corruption). With a private dump region there is no ordering
// requirement at all: first __syncthreads drains vmcnt; dump is never read.
// LDS 63.5KB -> 67.5KB, still 2 blocks/CU.
// Theory under test (R5): mega is fetch-latency/MLP-bound at ~230-280 GB/s
// (16.5MB -> ~70us of its 92us); the 48-deep async burst per wave raises
// lines-in-flight ~20x; subsequent fragment loads become L2 hits.

typedef short  s16x8 __attribute__((ext_vector_type(8)));
typedef short  s16x4 __attribute__((ext_vector_type(4)));
typedef float  f32x4 __attribute__((ext_vector_type(4)));

__device__ __forceinline__ unsigned short f2bf(float f) {
    union { float f; unsigned u; } v; v.f = f;
    unsigned r = v.u + 0x7FFFu + ((v.u >> 16) & 1u);   // RNE
    return (unsigned short)(r >> 16);
}
__device__ __forceinline__ float bf2f(unsigned short u) {
    return __uint_as_float(((unsigned)u) << 16);
}
// async global->LDS prefetch, 16B per lane, fire-and-forget
__device__ __forceinline__ void gll(const void* g, void* l) {
    __builtin_amdgcn_global_load_lds(
        (const __attribute__((address_space(1))) unsigned int*)g,
        (__attribute__((address_space(3))) unsigned int*)l, 16, 0, 0);
}

// ---------------------------------------------------------------------------
// prep: [0,512) W transpose f32->bf16 ; [512,1536) query->Qb ;
//       [1536,2560) key_hist->Khb   (unchanged, verified)
// ---------------------------------------------------------------------------
__global__ __launch_bounds__(256) void prep(
    const float* __restrict__ W, const float* __restrict__ query,
    const float* __restrict__ key_hist,
    short* __restrict__ Wtb, short* __restrict__ Qb, short* __restrict__ Khb)
{
    __shared__ float s[32][33];
    const int bx = blockIdx.x, t = threadIdx.x;
    if (bx < 512) {
        const int n0 = (bx & 63) * 32, k0 = (bx >> 6) * 32;
        const int c = t & 31, r0 = t >> 5;
        #pragma unroll
        for (int p = 0; p < 4; ++p) {
            const int r = r0 + p * 8;
            s[r][c] = W[(size_t)(k0 + r) * 2048 + n0 + c];
        }
        __syncthreads();
        #pragma unroll
        for (int p = 0; p < 4; ++p) {
            const int r = r0 + p * 8;
            Wtb[(size_t)(n0 + r) * 256 + k0 + c] = (short)f2bf(s[c][r]);
        }
    } else {
        const int j = bx - 512;
        const bool isK = j >= 1024;
        const float* src = isK ? key_hist : query;
        short* dst = isK ? Khb : Qb;
        const int i4 = ((j & 1023) * 256 + t) * 4;
        const float4 v = *(const float4*)(src + i4);
        s16x4 o;
        o.x = (short)f2bf(v.x); o.y = (short)f2bf(v.y);
        o.z = (short)f2bf(v.z); o.w = (short)f2bf(v.w);
        *(s16x4*)(dst + i4) = o;
    }
}

// ---------------------------------------------------------------------------
// mega7b: one block per (h,b). LDS 67.5 KB -> 2 blocks/CU.
// ---------------------------------------------------------------------------
__global__ __launch_bounds__(256, 2) void mega7b(
    const float* __restrict__ query, const float* __restrict__ value_hist,
    const float* __restrict__ refp,
    const short* __restrict__ Qb, const short* __restrict__ Khb,
    const short* __restrict__ Wtb, const float* __restrict__ bias,
    float* __restrict__ out)
{
    const int h = blockIdx.x, b = blockIdx.y;
    const int t = threadIdx.x, lane = t & 63, wave = t >> 6;
    const int quad = lane >> 4, col = lane & 15;
    const int wq = wave * 16;

    __shared__ __align__(16) short VTl[32 * 136];   // V^T [d][p], 8704 B
    __shared__ __align__(16) short attLb[64 * 136]; // att probs bf16, 17408 B
    __shared__ __align__(16) float rpsL[512];       // refp rows, 2048 B
    __shared__ __align__(16) float AmU[9216];       // 36864 B: Bsl / Am / Amb
    __shared__ __align__(16) char  dumpL[4096];     // burst dump — NEVER read
    short* Bsl = (short*)AmU;                       // [4][64][72] bf16
    float* Am  = AmU;                               // [64][132] f32
    short* Amb = (short*)AmU;                       // [64][136] bf16

    // ================= Phase 0: stage VTl + rps =================
    {   // VTl[d][p]: values = [query rows | value_hist rows] h-slice, transposed
        const int p = t >> 1, hf = (t & 1) * 16;
        const float* src = ((p < 64) ? query : value_hist) +
                           (size_t)(b * 64 + (p & 63)) * 256 + h * 32 + hf;
        #pragma unroll
        for (int u = 0; u < 4; ++u) {
            const float4 v = *(const float4*)(src + 4 * u);
            VTl[(hf + 4 * u + 0) * 136 + p] = (short)f2bf(v.x);
            VTl[(hf + 4 * u + 1) * 136 + p] = (short)f2bf(v.y);
            VTl[(hf + 4 * u + 2) * 136 + p] = (short)f2bf(v.z);
            VTl[(hf + 4 * u + 3) * 136 + p] = (short)f2bf(v.w);
        }
    }
    rpsL[t]       = refp[(size_t)b * 512 + t];
    rpsL[t + 256] = refp[(size_t)b * 512 + t + 256];

    // ================= Phase P: MLP burst (async L2-warm) =================
    // 48 fire-and-forget global_load_lds per wave into dumpL (private, never
    // read -> no ordering/aliasing hazard; first __syncthreads drains vmcnt).
    {
        char* dump = dumpL + wave * 1024;           // 1KB private dump/wave
        // Wtb h-slice: 256 rows x 512B; wave quarter = 64 rows = 32 instrs
        const short* wsl = Wtb + ((size_t)(h * 256 + wave * 64)) * 256;
        #pragma unroll
        for (int i = 0; i < 32; ++i)
            gll(wsl + i * 512 + lane * 8, dump);
        // Qb rows [b*64, +64): wave quarter = 16 rows = 8 instrs
        const short* qsl = Qb + ((size_t)(b * 64 + wave * 16)) * 256;
        #pragma unroll
        for (int i = 0; i < 8; ++i)
            gll(qsl + i * 512 + lane * 8, dump);
        // Khb rows [b*64, +64): wave quarter = 8 instrs
        const short* ksl = Khb + ((size_t)(b * 64 + wave * 16)) * 256;
        #pragma unroll
        for (int i = 0; i < 8; ++i)
            gll(ksl + i * 512 + lane * 8, dump);
    }

    // ================= Phase 1: logits + softmax -> attLb =================
    {
        const s16x8 aq = *(const s16x8*)(Qb +
            ((size_t)b * 64 + wq + col) * 256 + h * 32 + quad * 8);
        f32x4 lacc[8];
        #pragma unroll
        for (int t8 = 0; t8 < 8; ++t8) {
            const short* src = (t8 < 4)
                ? (Qb  + ((size_t)b * 64 + 16 * t8 + col) * 256)
                : (Khb + ((size_t)b * 64 + 16 * (t8 - 4) + col) * 256);
            const s16x8 bk = *(const s16x8*)(src + h * 32 + quad * 8);
            const f32x4 z = {0.f, 0.f, 0.f, 0.f};
            lacc[t8] = __builtin_amdgcn_mfma_f32_16x16x32_bf16(aq, bk, z, 0, 0, 0);
        }
        #pragma unroll
        for (int r = 0; r < 4; ++r) {
            float m = lacc[0][r];
            #pragma unroll
            for (int t8 = 1; t8 < 8; ++t8) m = fmaxf(m, lacc[t8][r]);
            #pragma unroll
            for (int s = 1; s < 16; s <<= 1) m = fmaxf(m, __shfl_xor(m, s, 64));
            float e[8], ssum = 0.f;
            #pragma unroll
            for (int t8 = 0; t8 < 8; ++t8) {
                e[t8] = __expf(lacc[t8][r] - m); ssum += e[t8];
            }
            #pragma unroll
            for (int s = 1; s < 16; s <<= 1) ssum += __shfl_xor(ssum, s, 64);
            const float inv = 1.0f / ssum;
            const int q = wq + 4 * quad + r;
            #pragma unroll
            for (int t8 = 0; t8 < 8; ++t8)
                attLb[q * 136 + 16 * t8 + col] = (short)f2bf(e[t8] * inv);
        }
    }

    // ================= Phase 2: offsets GEMM (OFF in registers) =============
    // wave owns n' in [64*wave, +64): acc[mi][nj]; q = 16mi+4quad+reg,
    // n' = 64*wave + 16nj + col.
    f32x4 acc[4][4] = {};
    for (int kq = 0; kq < 4; ++kq) {
        s16x8 afp[4][2];                        // A-frags direct from Qb (L2)
        #pragma unroll
        for (int mi = 0; mi < 4; ++mi)
            #pragma unroll
            for (int ks = 0; ks < 2; ++ks)
                afp[mi][ks] = *(const s16x8*)(Qb +
                    ((size_t)b * 64 + 16 * mi + col) * 256
                    + kq * 64 + ks * 32 + quad * 8);
        #pragma unroll
        for (int u = 0; u < 8; ++u) {           // stage Bsl[4][64][72] <- Wtb
            const int g = t + 256 * u;
            const int w = g >> 9, rowu = (g >> 3) & 63, koff = (g & 7) * 8;
            *(s16x8*)&Bsl[(w * 64 + rowu) * 72 + koff] =
                *(const s16x8*)(Wtb + (size_t)(h * 256 + w * 64 + rowu) * 256
                                + kq * 64 + koff);
        }
        __syncthreads();
        #pragma unroll
        for (int ks = 0; ks < 2; ++ks) {
            s16x8 bf[4];
            #pragma unroll
            for (int nj = 0; nj < 4; ++nj)
                bf[nj] = *(const s16x8*)&Bsl[(wave * 64 + 16 * nj + col) * 72
                                             + ks * 32 + quad * 8];
            #pragma unroll
            for (int mi = 0; mi < 4; ++mi)
                #pragma unroll
                for (int nj = 0; nj < 4; ++nj)
                    acc[mi][nj] = __builtin_amdgcn_mfma_f32_16x16x32_bf16(
                        afp[mi][ks], bf[nj], acc[mi][nj], 0, 0, 0);
        }
        __syncthreads();
    }

    // ================= Phase 3: zero Am, scatter =================
    {
        #pragma unroll
        for (int u = 0; u < 33; ++u) AmU[t + 256 * u] = 0.f;
    }
    __syncthreads();
    {
        const int i   = col >> 1;          // f-sub 0..7 ; rp level = (f&3)
        const int par = col & 1;           // 0: regs {0,1}, 1: regs {2,3}
        const int base = 32 * wave;        // image level = f>>5 = wave
        #pragma unroll
        for (int nj = 0; nj < 4; ++nj) {
            const float bj = bias[h * 256 + wave * 64 + 16 * nj + col];
            const int f = 32 * wave + 8 * nj + i;
            #pragma unroll
            for (int mi = 0; mi < 4; ++mi) {
                float v[4], p[4];
                #pragma unroll
                for (int r = 0; r < 4; ++r) v[r] = acc[mi][nj][r] + bj;
                #pragma unroll
                for (int r = 0; r < 4; ++r) p[r] = __shfl_xor(v[r], 1, 64);
                #pragma unroll
                for (int rs = 0; rs < 2; ++rs) {
                    const int r = par * 2 + rs;
                    const float ox = par ? p[r] : v[r];
                    const float oy = par ? v[r] : p[r];
                    const int q = 16 * mi + 4 * quad + r;
                    const float2 rp = *(const float2*)&rpsL[q * 8 + (i & 3) * 2];
                    const float a = bf2f((unsigned short)attLb[q * 136 + f]);
                    const float gx = 8.f * (rp.x + ox * 0.125f) - 0.5f;
                    const float gy = 4.f * (rp.y + oy * 0.25f) - 0.5f;
                    const float x0f = floorf(gx), y0f = floorf(gy);
                    const float wx = gx - x0f, wy = gy - y0f;
                    const int x0 = (int)x0f, y0 = (int)y0f;
                    float* rowW = &Am[q * 132 + base];
                    const bool xv0 = (x0 >= 0) && (x0 < 8);
                    const bool xv1 = (x0 >= -1) && (x0 < 7);
                    const bool yv0 = (y0 >= 0) && (y0 < 4);
                    const bool yv1 = (y0 >= -1) && (y0 < 3);
                    if (xv0 && yv0) unsafeAtomicAdd(&rowW[y0 * 8 + x0],           a * (1.f - wx) * (1.f - wy));
                    if (xv1 && yv0) unsafeAtomicAdd(&rowW[y0 * 8 + x0 + 1],       a * wx * (1.f - wy));
                    if (xv0 && yv1) unsafeAtomicAdd(&rowW[(y0 + 1) * 8 + x0],     a * (1.f - wx) * wy);
                    if (xv1 && yv1) unsafeAtomicAdd(&rowW[(y0 + 1) * 8 + x0 + 1], a * wx * wy);
                }
            }
        }
    }
    __syncthreads();

    // ================= Phase 4: Am -> bf16, AV, output =================
    {
        const int cq = t >> 2, cc = (t & 3) * 32;
        float vreg[32];
        #pragma unroll
        for (int u = 0; u < 8; ++u) {
            const float4 v = *(const float4*)&Am[cq * 132 + cc + 4 * u];
            vreg[4 * u + 0] = v.x; vreg[4 * u + 1] = v.y;
            vreg[4 * u + 2] = v.z; vreg[4 * u + 3] = v.w;
        }
        __syncthreads();
        #pragma unroll
        for (int u = 0; u < 4; ++u) {
            s16x8 o;
            #pragma unroll
            for (int j = 0; j < 8; ++j) o[j] = (short)f2bf(vreg[u * 8 + j]);
            *(s16x8*)&Amb[cq * 136 + cc + u * 8] = o;
        }
    }
    __syncthreads();
    {
        f32x4 oacc[2] = {};
        #pragma unroll
        for (int ks = 0; ks < 4; ++ks) {
            const s16x8 af = *(const s16x8*)&Amb[(wq + col) * 136 + ks * 32 + quad * 8];
            #pragma unroll
            for (int n2 = 0; n2 < 2; ++n2) {
                const s16x8 bv = *(const s16x8*)&VTl[(n2 * 16 + col) * 136
                                                     + ks * 32 + quad * 8];
                oacc[n2] = __builtin_amdgcn_mfma_f32_16x16x32_bf16(af, bv, oacc[n2], 0, 0, 0);
            }
        }
        #pragma unroll
        for (int n2 = 0; n2 < 2; ++n2) {
            const int d = h * 32 + n2 * 16 + col;
            #pragma unroll
            for (int pr = 0; pr < 2; ++pr) {
                const float avg = 0.5f * (oacc[n2][2 * pr] + oacc[n2][2 * pr + 1]);
                const int pj = wave * 8 + quad * 2 + pr;
                const size_t re = ((size_t)b * 64 + pj) * 256 + d;
                const size_t ro = ((size_t)b * 64 + pj + 32) * 256 + d;
                out[re] = query[re] + avg;
                out[ro] = query[ro] + avg;
            }
        }
    }
}

extern "C" void kernel_launch(void* const* d_in, const int* in_sizes, int n_in,
                              void* d_out, int out_size, void* d_ws, size_t ws_size,
                              hipStream_t stream) {
    (void)in_sizes; (void)n_in; (void)out_size; (void)ws_size;
    const float* query      = (const float*)d_in[0];
    const float* key_hist   = (const float*)d_in[1];
    const float* value_hist = (const float*)d_in[2];
    const float* refp       = (const float*)d_in[3];
    const float* W_off      = (const float*)d_in[5];
    const float* b_off      = (const float*)d_in[6];

    char* ws = (char*)d_ws;
    short* Wtb = (short*)(ws);                 // 1 MB
    short* Qb  = (short*)(ws + (1u << 20));    // 2 MB
    short* Khb = (short*)(ws + (3u << 20));    // 2 MB
    float* out = (float*)d_out;

    prep<<<2560, 256, 0, stream>>>(W_off, query, key_hist, Wtb, Qb, Khb);
    mega7b<<<dim3(8, 64), 256, 0, stream>>>(query, value_hist, refp,
                                            Qb, Khb, Wtb, b_off, out);
}